// Round 1
// baseline (96.988 us; speedup 1.0000x reference)
//
#include <hip/hip_runtime.h>
#include <math.h>

#define LUT_N 4096  // intervals; LUT_N+1 entries

// d_ws layout (floats):
//  [0..255]         K[a][b][c][d]: Pauli coefficients of O'' = U^dag Z0 U,
//                   a<->wire0 ... d<->wire3, index = ((a*4+b)*4+c)*4+d.
//                   U = all x-independent gates (layer0 RY/RZ, CNOTs, RX; layer1
//                   RY/RZ, CNOTs, RX). Measurement is then a product-state
//                   contraction: q = sum K * E0[a]E1[b]E2[c]E3[d].
//  [256..256+LUT_N] f(q) = MLP+sigmoid sampled at q = k/2048 - 1

__device__ __forceinline__ float mlp_eval(float q,
                                          const float* __restrict__ W1, const float* __restrict__ b1,
                                          const float* __restrict__ W2, const float* __restrict__ b2,
                                          const float* __restrict__ W3, const float* __restrict__ b3,
                                          const float* __restrict__ W4, const float* __restrict__ b4) {
  float h1[32];
#pragma unroll
  for (int j = 0; j < 32; ++j) h1[j] = fmaxf(0.f, fmaf(q, W1[j], b1[j]));
  float h2[16];
#pragma unroll
  for (int k = 0; k < 16; ++k) {
    float acc = b2[k];
#pragma unroll
    for (int j = 0; j < 32; ++j) acc = fmaf(W2[k * 32 + j], h1[j], acc);
    h2[k] = fmaxf(0.f, acc);
  }
  float h3[8];
#pragma unroll
  for (int k = 0; k < 8; ++k) {
    float acc = b3[k];
#pragma unroll
    for (int j = 0; j < 16; ++j) acc = fmaf(W3[k * 16 + j], h2[j], acc);
    h3[k] = fmaxf(0.f, acc);
  }
  float acc = b4[0];
#pragma unroll
  for (int j = 0; j < 8; ++j) acc = fmaf(W4[j], h3[j], acc);
  return 1.f / (1.f + expf(-acc));
}

// Apply 1q gate G (complex 2x2) on wire w to 16x16 matrix U in LDS: U <- G*U.
// Thread owns element (r,c). Wire w lives at bit (3-w) of the row index.
__device__ __forceinline__ void g1q(float (*Ur)[16], float (*Ui)[16], int r, int c, int w,
                                    float u00r, float u00i, float u01r, float u01i,
                                    float u10r, float u10i, float u11r, float u11i) {
  const int tb = 8 >> w;
  const int bit = (r & tb) ? 1 : 0;
  const int rp = r ^ tb;
  float ar = Ur[r][c], ai = Ui[r][c];
  float br = Ur[rp][c], bi = Ui[rp][c];
  __syncthreads();  // all reads done before any write
  float dr = bit ? u11r : u00r, di = bit ? u11i : u00i;
  float fr = bit ? u10r : u01r, fi = bit ? u10i : u01i;
  Ur[r][c] = dr * ar - di * ai + fr * br - fi * bi;
  Ui[r][c] = dr * ai + di * ar + fr * bi + fi * br;
  __syncthreads();
}

// CNOT(control cc, target tt) as row permutation: newU[r] = U[p[r]],
// p[r] = r ^ (bit(r,3-cc) << (3-tt))  (matches reference _cnot_perm + flat[:,p]).
__device__ __forceinline__ void gcnot(float (*Ur)[16], float (*Ui)[16], int r, int c,
                                      int cc, int tt) {
  int src = r ^ ((((r >> (3 - cc)) & 1)) << (3 - tt));
  float ar = Ur[src][c], ai = Ui[src][c];
  __syncthreads();
  Ur[r][c] = ar; Ui[r][c] = ai;
  __syncthreads();
}

__global__ void qnn_setup(const float* __restrict__ qw,
                          const float* __restrict__ W1, const float* __restrict__ b1,
                          const float* __restrict__ W2, const float* __restrict__ b2,
                          const float* __restrict__ W3, const float* __restrict__ b3,
                          const float* __restrict__ W4, const float* __restrict__ b4,
                          float* __restrict__ ws) {
  if (blockIdx.x < 16) {
    // LUT entries 0..4095
    int gid = blockIdx.x * 256 + threadIdx.x;
    float q = (float)(gid - LUT_N / 2) * (2.0f / LUT_N);
    ws[256 + gid] = mlp_eval(q, W1, b1, W2, b2, W3, b3, W4, b4);
    return;
  }

  // Block 16: build U (16x16 complex) = full x-independent circuit, then
  // O'' = U^dag Z0 U, then project onto the 256 Pauli strings.
  __shared__ float Ur[16][16], Ui[16][16], Opr[16][16], Opi[16][16];
  const int t = threadIdx.x;
  const int r = t >> 4, c = t & 15;

  Ur[r][c] = (r == c) ? 1.f : 0.f;
  Ui[r][c] = 0.f;
  __syncthreads();

#pragma unroll
  for (int l = 0; l < 2; ++l) {
    // per-wire RY(qw[l*4+w]) then RZ(qw[l*4+w+4])
#pragma unroll
    for (int w = 0; w < 4; ++w) {
      float ty = qw[l * 4 + w];
      float sy = sinf(0.5f * ty), cy = cosf(0.5f * ty);
      g1q(Ur, Ui, r, c, w, cy, 0.f, -sy, 0.f, sy, 0.f, cy, 0.f);
      float tz = qw[l * 4 + w + 4];
      float sz = sinf(0.5f * tz), cz = cosf(0.5f * tz);
      g1q(Ur, Ui, r, c, w, cz, -sz, 0.f, 0.f, 0.f, 0.f, cz, sz);
    }
    // CNOT block (0,1)(0,2)(0,3)(1,2)(1,3)(2,3)
    gcnot(Ur, Ui, r, c, 0, 1);
    gcnot(Ur, Ui, r, c, 0, 2);
    gcnot(Ur, Ui, r, c, 0, 3);
    gcnot(Ur, Ui, r, c, 1, 2);
    gcnot(Ur, Ui, r, c, 1, 3);
    gcnot(Ur, Ui, r, c, 2, 3);
    // per-wire RX(qw[l*4+w+8])
#pragma unroll
    for (int w = 0; w < 4; ++w) {
      float tx = qw[l * 4 + w + 8];
      float sx = sinf(0.5f * tx), cx = cosf(0.5f * tx);
      g1q(Ur, Ui, r, c, w, cx, 0.f, 0.f, -sx, 0.f, -sx, cx, 0.f);
    }
  }

  // O''[r][c] = sum_k conj(U[k][r]) * z_k * U[k][c], z_k = +1 (k<8) / -1
  float opr = 0.f, opi = 0.f;
#pragma unroll
  for (int k = 0; k < 16; ++k) {
    float zk = (k < 8) ? 1.f : -1.f;
    float ar = Ur[k][r], ai = -Ui[k][r];
    float br = Ur[k][c], bi = Ui[k][c];
    opr += zk * (ar * br - ai * bi);
    opi += zk * (ar * bi + ai * br);
  }
  __syncthreads();
  Opr[r][c] = opr;
  Opi[r][c] = opi;
  __syncthreads();

  // K[t] = Re Tr(O'' * P)/16, P = P_a x P_b x P_c x P_d, t=(a<<6)|(b<<4)|(c<<2)|d.
  // Paulis have one nonzero per row: for row j, column i(j) with coeff in {±1,±i}.
  const int p0 = (t >> 6) & 3, p1 = (t >> 4) & 3, p2 = (t >> 2) & 3, p3 = t & 3;
  const int pw[4] = {p0, p1, p2, p3};
  float sr = 0.f;
#pragma unroll
  for (int j = 0; j < 16; ++j) {
    int i = j;
    float cr = 1.f, ci = 0.f;
#pragma unroll
    for (int w = 0; w < 4; ++w) {
      int jb = (j >> (3 - w)) & 1;
      int p = pw[w];
      if (p == 1) {                      // X: col = row^1, coeff 1
        i ^= 8 >> w;
      } else if (p == 2) {               // Y: col = row^1, coeff -i (jb=0) / +i (jb=1)
        i ^= 8 >> w;
        float f = jb ? 1.f : -1.f;       // coeff *= f*i
        float nr = -ci * f, ni = cr * f;
        cr = nr; ci = ni;
      } else if (p == 3) {               // Z: col = row, coeff 1-2*jb
        float f = jb ? -1.f : 1.f;
        cr *= f; ci *= f;
      }
    }
    sr += Opr[i][j] * cr - Opi[i][j] * ci;  // Re(O''[i][j] * coeff)
  }
  ws[t] = sr * (1.f / 16.f);

  // LUT tail entry (q = +1)
  if (t == 0) ws[256 + LUT_N] = mlp_eval(1.f, W1, b1, W2, b2, W3, b3, W4, b4);
}

__global__ __launch_bounds__(256) void qnn_kernel(
    const float* __restrict__ x, const float* __restrict__ ws,
    float* __restrict__ out, int B) {
  int b = blockIdx.x * blockDim.x + threadIdx.x;
  if (b >= B) return;

  float4 xv = reinterpret_cast<const float4*>(x)[b];
  float xs[4] = {xv.x, xv.y, xv.z, xv.w};

  // Per-wire Pauli expectations of RZ(x)RX(x)|0>:
  //   <X> = sin^2 x, <Y> = -sin x cos x, <Z> = cos x   (full angle!)
  float E[4][4];
#pragma unroll
  for (int w = 0; w < 4; ++w) {
    float s, c;
    __sincosf(xs[w], &s, &c);
    E[w][0] = 1.f;
    E[w][1] = s * s;
    E[w][2] = -s * c;
    E[w][3] = c;
  }

  // q = sum_{abcd} K[abcd] E0[a] E1[b] E2[c] E3[d]  (factorized: 276 FMA)
  float q = 0.f;
#pragma unroll
  for (int a = 0; a < 4; ++a) {
    float ta = 0.f;
#pragma unroll
    for (int bb = 0; bb < 4; ++bb) {
      float tb = 0.f;
#pragma unroll
      for (int cc = 0; cc < 4; ++cc) {
        const float* kp = ws + (((a * 4 + bb) * 4 + cc) * 4);
        float tc = fmaf(kp[3], E[3][3],
                   fmaf(kp[2], E[3][2],
                   fmaf(kp[1], E[3][1], kp[0])));
        tb = fmaf(tc, E[2][cc], tb);
      }
      ta = fmaf(tb, E[1][bb], ta);
    }
    q = fmaf(ta, E[0][a], q);
  }

  // MLP via LUT + linear interp (f is PWL+sigmoid; err ~2e-4 << 1.1e-2 thr)
  const float* lut = ws + 256;
  float tt = fmaf(q, (float)(LUT_N / 2), (float)(LUT_N / 2));
  tt = fminf(fmaxf(tt, 0.f), (float)LUT_N);
  int i0 = min((int)tt, LUT_N - 1);
  float frac = tt - (float)i0;
  float f0 = lut[i0], f1 = lut[i0 + 1];
  out[b] = fmaf(frac, f1 - f0, f0);
}

extern "C" void kernel_launch(void* const* d_in, const int* in_sizes, int n_in,
                              void* d_out, int out_size, void* d_ws, size_t ws_size,
                              hipStream_t stream) {
  const float* x  = (const float*)d_in[0];
  const float* qw = (const float*)d_in[1];
  const float* W1 = (const float*)d_in[2];
  const float* b1 = (const float*)d_in[3];
  const float* W2 = (const float*)d_in[4];
  const float* b2 = (const float*)d_in[5];
  const float* W3 = (const float*)d_in[6];
  const float* b3 = (const float*)d_in[7];
  const float* W4 = (const float*)d_in[8];
  const float* b4 = (const float*)d_in[9];
  float* out = (float*)d_out;
  float* ws  = (float*)d_ws;

  qnn_setup<<<17, 256, 0, stream>>>(qw, W1, b1, W2, b2, W3, b3, W4, b4, ws);

  const int B = in_sizes[0] / 4;
  const int block = 256;
  const int grid = (B + block - 1) / block;
  qnn_kernel<<<grid, block, 0, stream>>>(x, ws, out, B);
}

// Round 2
// 88.750 us; speedup vs baseline: 1.0928x; 1.0928x over previous
//
#include <hip/hip_runtime.h>
#include <math.h>

#define LUT_N 4096  // intervals; LUT_N+1 entries

// d_ws layout (floats):
//  [0..255]         K[a][b][c][d]: Pauli coefficients of O'' = U^dag Z0 U,
//                   a<->wire0 ... d<->wire3, index = ((a*4+b)*4+c)*4+d.
//                   U = all x-independent gates (layer0 RY/RZ, CNOTs, RX; layer1
//                   RY/RZ, CNOTs, RX). Measurement is then a product-state
//                   contraction: q = sum K * E0[a]E1[b]E2[c]E3[d].
//  [256..256+LUT_N] f(q) = MLP+sigmoid sampled at q = k/2048 - 1

__device__ __forceinline__ float mlp_eval(float q,
                                          const float* __restrict__ W1, const float* __restrict__ b1,
                                          const float* __restrict__ W2, const float* __restrict__ b2,
                                          const float* __restrict__ W3, const float* __restrict__ b3,
                                          const float* __restrict__ W4, const float* __restrict__ b4) {
  float h1[32];
#pragma unroll
  for (int j = 0; j < 32; ++j) h1[j] = fmaxf(0.f, fmaf(q, W1[j], b1[j]));
  float h2[16];
#pragma unroll
  for (int k = 0; k < 16; ++k) {
    float acc = b2[k];
#pragma unroll
    for (int j = 0; j < 32; ++j) acc = fmaf(W2[k * 32 + j], h1[j], acc);
    h2[k] = fmaxf(0.f, acc);
  }
  float h3[8];
#pragma unroll
  for (int k = 0; k < 8; ++k) {
    float acc = b3[k];
#pragma unroll
    for (int j = 0; j < 16; ++j) acc = fmaf(W3[k * 16 + j], h2[j], acc);
    h3[k] = fmaxf(0.f, acc);
  }
  float acc = b4[0];
#pragma unroll
  for (int j = 0; j < 8; ++j) acc = fmaf(W4[j], h3[j], acc);
  return 1.f / (1.f + expf(-acc));
}

// In-register 1q gate on a 16-row column: rows r / r^TB mix. Compile-time
// indices only — fully unrolled, no LDS, no barriers.
template <int TB>
__device__ __forceinline__ void apply16(float (&ur)[16], float (&ui)[16],
                                        float u00r, float u00i, float u01r, float u01i,
                                        float u10r, float u10i, float u11r, float u11i) {
#pragma unroll
  for (int i = 0; i < 16; ++i) {
    if (i & TB) continue;
    const int j = i | TB;
    float ar = ur[i], ai = ui[i], br = ur[j], bi = ui[j];
    float nr = u00r * ar - u00i * ai + u01r * br - u01i * bi;
    float ni = u00r * ai + u00i * ar + u01r * bi + u01i * br;
    float mr = u10r * ar - u10i * ai + u11r * br - u11i * bi;
    float mi = u10r * ai + u10i * ar + u11r * bi + u11i * br;
    ur[i] = nr; ui[i] = ni; ur[j] = mr; ui[j] = mi;
  }
}

// CNOT(control mask CB, target mask TB) on rows: pure register rename.
template <int CB, int TB>
__device__ __forceinline__ void cnot16(float (&ur)[16], float (&ui)[16]) {
#pragma unroll
  for (int i = 0; i < 16; ++i) {
    if (!(i & CB)) continue;
    if (i & TB) continue;
    const int j = i | TB;
    float tr = ur[i], ti = ui[i];
    ur[i] = ur[j]; ui[i] = ui[j];
    ur[j] = tr;    ui[j] = ti;
  }
}

__global__ void qnn_setup(const float* __restrict__ qw,
                          const float* __restrict__ W1, const float* __restrict__ b1,
                          const float* __restrict__ W2, const float* __restrict__ b2,
                          const float* __restrict__ W3, const float* __restrict__ b3,
                          const float* __restrict__ W4, const float* __restrict__ b4,
                          float* __restrict__ ws) {
  if (blockIdx.x < 16) {
    // LUT entries 0..4095
    int gid = blockIdx.x * 256 + threadIdx.x;
    float q = (float)(gid - LUT_N / 2) * (2.0f / LUT_N);
    ws[256 + gid] = mlp_eval(q, W1, b1, W2, b2, W3, b3, W4, b4);
    return;
  }

  // Block 16: build U (16x16 complex) = full x-independent circuit, then
  // O'' = U^dag Z0 U, then project onto the 256 Pauli strings.
  // Phase 1 (barrier-free): lanes 0..15 each own one COLUMN of U in registers;
  // gates are row-butterflies (in-register), CNOTs are register renames.
  __shared__ float sUr[16][17], sUi[16][17], Opr[16][17], Opi[16][17];
  const int t = threadIdx.x;
  const int r = t >> 4, c = t & 15;

  if (t < 16) {
    float Ur[16], Ui[16];
#pragma unroll
    for (int k = 0; k < 16; ++k) { Ur[k] = (k == t) ? 1.f : 0.f; Ui[k] = 0.f; }

    // A = RZ(tz)*RY(ty): [[(cz-isz)cy, -(cz-isz)sy], [(cz+isz)sy, (cz+isz)cy]]
#define ZY_GATE(l, w, TB)                                                     \
    {                                                                         \
      float sy, cy, sz, cz;                                                   \
      __sincosf(0.5f * qw[(l) * 4 + (w)], &sy, &cy);                          \
      __sincosf(0.5f * qw[(l) * 4 + (w) + 4], &sz, &cz);                      \
      apply16<TB>(Ur, Ui, cz * cy, -sz * cy, -cz * sy, sz * sy,               \
                  cz * sy, sz * sy, cz * cy, sz * cy);                        \
    }
    // RX(tx): [[cx, -i sx], [-i sx, cx]]
#define X_GATE(l, w, TB)                                                      \
    {                                                                         \
      float sx, cx;                                                           \
      __sincosf(0.5f * qw[(l) * 4 + (w) + 8], &sx, &cx);                      \
      apply16<TB>(Ur, Ui, cx, 0.f, 0.f, -sx, 0.f, -sx, cx, 0.f);              \
    }
#define LAYER(l)                                                              \
    ZY_GATE(l, 0, 8) ZY_GATE(l, 1, 4) ZY_GATE(l, 2, 2) ZY_GATE(l, 3, 1)       \
    cnot16<8, 4>(Ur, Ui); cnot16<8, 2>(Ur, Ui); cnot16<8, 1>(Ur, Ui);         \
    cnot16<4, 2>(Ur, Ui); cnot16<4, 1>(Ur, Ui); cnot16<2, 1>(Ur, Ui);         \
    X_GATE(l, 0, 8) X_GATE(l, 1, 4) X_GATE(l, 2, 2) X_GATE(l, 3, 1)

    LAYER(0)
    LAYER(1)
#undef LAYER
#undef X_GATE
#undef ZY_GATE

#pragma unroll
    for (int k = 0; k < 16; ++k) { sUr[k][t] = Ur[k]; sUi[k][t] = Ui[k]; }
  }
  __syncthreads();

  // O''[r][c] = sum_k conj(U[k][r]) * z_k * U[k][c], z_k = +1 (k<8) / -1
  float opr = 0.f, opi = 0.f;
#pragma unroll
  for (int k = 0; k < 16; ++k) {
    float zk = (k < 8) ? 1.f : -1.f;
    float ar = sUr[k][r], ai = -sUi[k][r];
    float br = sUr[k][c], bi = sUi[k][c];
    opr += zk * (ar * br - ai * bi);
    opi += zk * (ar * bi + ai * br);
  }
  Opr[r][c] = opr;
  Opi[r][c] = opi;
  __syncthreads();

  // K[t] = Re Tr(O'' * P)/16, P = P_a x P_b x P_c x P_d, t=(a<<6)|(b<<4)|(c<<2)|d.
  // Paulis have one nonzero per row: for row j, column i(j) with coeff in {±1,±i}.
  const int p0 = (t >> 6) & 3, p1 = (t >> 4) & 3, p2 = (t >> 2) & 3, p3 = t & 3;
  const int pw[4] = {p0, p1, p2, p3};
  float sr = 0.f;
#pragma unroll
  for (int j = 0; j < 16; ++j) {
    int i = j;
    float cr = 1.f, ci = 0.f;
#pragma unroll
    for (int w = 0; w < 4; ++w) {
      int jb = (j >> (3 - w)) & 1;
      int p = pw[w];
      if (p == 1) {                      // X: col = row^1, coeff 1
        i ^= 8 >> w;
      } else if (p == 2) {               // Y: col = row^1, coeff -i (jb=0) / +i (jb=1)
        i ^= 8 >> w;
        float f = jb ? 1.f : -1.f;       // coeff *= f*i
        float nr = -ci * f, ni = cr * f;
        cr = nr; ci = ni;
      } else if (p == 3) {               // Z: col = row, coeff 1-2*jb
        float f = jb ? -1.f : 1.f;
        cr *= f; ci *= f;
      }
    }
    sr += Opr[i][j] * cr - Opi[i][j] * ci;  // Re(O''[i][j] * coeff)
  }
  ws[t] = sr * (1.f / 16.f);

  // LUT tail entry (q = +1)
  if (t == 0) ws[256 + LUT_N] = mlp_eval(1.f, W1, b1, W2, b2, W3, b3, W4, b4);
}

__global__ __launch_bounds__(256) void qnn_kernel(
    const float* __restrict__ x, const float* __restrict__ ws,
    float* __restrict__ out, int B) {
  int b = blockIdx.x * blockDim.x + threadIdx.x;
  if (b >= B) return;

  float4 xv = reinterpret_cast<const float4*>(x)[b];
  float xs[4] = {xv.x, xv.y, xv.z, xv.w};

  // Per-wire Pauli expectations of RZ(x)RX(x)|0>:
  //   <X> = sin^2 x, <Y> = -sin x cos x, <Z> = cos x   (full angle!)
  float E[4][4];
#pragma unroll
  for (int w = 0; w < 4; ++w) {
    float s, c;
    __sincosf(xs[w], &s, &c);
    E[w][0] = 1.f;
    E[w][1] = s * s;
    E[w][2] = -s * c;
    E[w][3] = c;
  }

  // q = sum_{abcd} K[abcd] E0[a] E1[b] E2[c] E3[d]  (factorized: 276 FMA)
  float q = 0.f;
#pragma unroll
  for (int a = 0; a < 4; ++a) {
    float ta = 0.f;
#pragma unroll
    for (int bb = 0; bb < 4; ++bb) {
      float tb = 0.f;
#pragma unroll
      for (int cc = 0; cc < 4; ++cc) {
        const float* kp = ws + (((a * 4 + bb) * 4 + cc) * 4);
        float tc = fmaf(kp[3], E[3][3],
                   fmaf(kp[2], E[3][2],
                   fmaf(kp[1], E[3][1], kp[0])));
        tb = fmaf(tc, E[2][cc], tb);
      }
      ta = fmaf(tb, E[1][bb], ta);
    }
    q = fmaf(ta, E[0][a], q);
  }

  // MLP via LUT + linear interp (f is PWL+sigmoid; err ~2e-4 << 1.1e-2 thr)
  const float* lut = ws + 256;
  float tt = fmaf(q, (float)(LUT_N / 2), (float)(LUT_N / 2));
  tt = fminf(fmaxf(tt, 0.f), (float)LUT_N);
  int i0 = min((int)tt, LUT_N - 1);
  float frac = tt - (float)i0;
  float f0 = lut[i0], f1 = lut[i0 + 1];
  out[b] = fmaf(frac, f1 - f0, f0);
}

extern "C" void kernel_launch(void* const* d_in, const int* in_sizes, int n_in,
                              void* d_out, int out_size, void* d_ws, size_t ws_size,
                              hipStream_t stream) {
  const float* x  = (const float*)d_in[0];
  const float* qw = (const float*)d_in[1];
  const float* W1 = (const float*)d_in[2];
  const float* b1 = (const float*)d_in[3];
  const float* W2 = (const float*)d_in[4];
  const float* b2 = (const float*)d_in[5];
  const float* W3 = (const float*)d_in[6];
  const float* b3 = (const float*)d_in[7];
  const float* W4 = (const float*)d_in[8];
  const float* b4 = (const float*)d_in[9];
  float* out = (float*)d_out;
  float* ws  = (float*)d_ws;

  qnn_setup<<<17, 256, 0, stream>>>(qw, W1, b1, W2, b2, W3, b3, W4, b4, ws);

  const int B = in_sizes[0] / 4;
  const int block = 256;
  const int grid = (B + block - 1) / block;
  qnn_kernel<<<grid, block, 0, stream>>>(x, ws, out, B);
}